// Round 2
// baseline (1011.404 us; speedup 1.0000x reference)
//
#include <hip/hip_runtime.h>
#include <hip/hip_bf16.h>
#include <stdint.h>

// ---------------------------------------------------------------------------
// O = softmax(q_n . k_n^T) @ keys_raw   (N=65536, K=4096, D=128)
// Transposed-MFMA scheme: S^T = Kn.Qn^T, O^T = V^T.P^T. Key order inside each
// staged 64-key tile is permuted (pi) so the S^T output registers ARE the PV
// B-fragment after exp+pack -> no P LDS round-trip. 64 q-rows per wave.
// kf from LDS (async-staged, double-buffered); vf direct from L2.
// ws: [0,1MB) knb bf16 [K][128] normalized; [1MB,2MB) vt bf16 [128][K] raw.
// ---------------------------------------------------------------------------

typedef __attribute__((ext_vector_type(8))) short bf16x8;
typedef __attribute__((ext_vector_type(4))) float f32x4;

#define MFMA16(a, b, c) __builtin_amdgcn_mfma_f32_16x16x32_bf16(a, b, c, 0, 0, 0)
#define ASYNC_CP16(gsrc, ldst)                                                  \
  __builtin_amdgcn_global_load_lds(                                             \
      (const __attribute__((address_space(1))) void*)(gsrc),                    \
      (__attribute__((address_space(3))) void*)(ldst), 16, 0, 0)

__device__ __forceinline__ unsigned pkbf(float lo, float hi) {
  union { __hip_bfloat162 h2; unsigned u; } v;
  v.h2 = __float22bfloat162_rn(float2{lo, hi});
  return v.u;
}
__device__ __forceinline__ unsigned short f2bf1(float x) {
  union { __hip_bfloat16 h; unsigned short s; } v;
  v.h = __float2bfloat16(x);
  return v.s;
}

// -------- prep_k: knb = normalize(keys) bf16 [K][128]; vt = keys^T bf16 -----
__global__ __launch_bounds__(256) void prep_k(const float* __restrict__ k,
                                              unsigned* __restrict__ knb,
                                              unsigned* __restrict__ vt, int K) {
  __shared__ unsigned short sV[128 * 66];   // transposed raw tile, padded
  const int tid = threadIdx.x;
  const int kbase = blockIdx.x * 64;
  const int keyl = tid >> 2;                // 0..63 local key
  const int dq = tid & 3;                   // d-quarter (32 floats)
  const int key = kbase + keyl;

  float f[32];
  const float4* src = (const float4*)(k + (size_t)key * 128 + dq * 32);
#pragma unroll
  for (int i = 0; i < 8; ++i) {
    float4 t = src[i];
    f[4 * i] = t.x; f[4 * i + 1] = t.y; f[4 * i + 2] = t.z; f[4 * i + 3] = t.w;
  }
  float ss = 0.f;
#pragma unroll
  for (int i = 0; i < 32; ++i) ss += f[i] * f[i];
  ss += __shfl_xor(ss, 1);
  ss += __shfl_xor(ss, 2);
  const float sc = ss > 0.f ? rsqrtf(ss) : 0.f;

  // normalized keys, plain [K][128] bf16, coalesced 16B stores
  uint4* dstk = (uint4*)(knb + (size_t)key * 64 + dq * 16);
#pragma unroll
  for (int i = 0; i < 4; ++i) {
    uint4 w;
    w.x = pkbf(f[8 * i + 0] * sc, f[8 * i + 1] * sc);
    w.y = pkbf(f[8 * i + 2] * sc, f[8 * i + 3] * sc);
    w.z = pkbf(f[8 * i + 4] * sc, f[8 * i + 5] * sc);
    w.w = pkbf(f[8 * i + 6] * sc, f[8 * i + 7] * sc);
    dstk[i] = w;
  }

  // raw keys -> LDS transposed
#pragma unroll
  for (int i = 0; i < 32; ++i) sV[(dq * 32 + i) * 66 + keyl] = f2bf1(f[i]);
  __syncthreads();

  // coalesced store of vt rows: thread t -> d=t>>1, key-half=t&1
  const int d = tid >> 1, kh = tid & 1;
  const unsigned short* row = &sV[d * 66 + kh * 32];
  uint4* dstv = (uint4*)(vt + ((size_t)d * K + kbase) / 2 + kh * 16);
#pragma unroll
  for (int i = 0; i < 4; ++i) {
    uint4 w;
    w.x = (unsigned)row[8 * i + 0] | ((unsigned)row[8 * i + 1] << 16);
    w.y = (unsigned)row[8 * i + 2] | ((unsigned)row[8 * i + 3] << 16);
    w.z = (unsigned)row[8 * i + 4] | ((unsigned)row[8 * i + 5] << 16);
    w.w = (unsigned)row[8 * i + 6] | ((unsigned)row[8 * i + 7] << 16);
    dstv[i] = w;
  }
}

// ----------------------------- fused attention ------------------------------
// 128 thr = 2 waves; wave owns 64 q-rows. grid = N/128 = 512.
__global__ __launch_bounds__(128, 2) void attn_main(
    const float* __restrict__ q, const char* __restrict__ knb,
    const char* __restrict__ vt, float* __restrict__ out, int K) {
  __shared__ __align__(16) char sK[2][16384];   // double-buffered Kn tile
  const int tid = threadIdx.x;
  const int wave = tid >> 6, lane = tid & 63;
  const int g = lane >> 4, c = lane & 15;
  const int qrow0 = blockIdx.x * 128 + wave * 64;

  // ---- Q fragments: normalized * log2e, resident in VGPRs -----------------
  bf16x8 qf[4][4];   // [qb][ks]
#pragma unroll
  for (int qb = 0; qb < 4; ++qb) {
    const float* qr = q + (size_t)(qrow0 + qb * 16 + c) * 128;
    float f[32];
#pragma unroll
    for (int ks = 0; ks < 4; ++ks) {
      float4 a = *(const float4*)(qr + ks * 32 + g * 8);
      float4 b = *(const float4*)(qr + ks * 32 + g * 8 + 4);
      f[ks * 8 + 0] = a.x; f[ks * 8 + 1] = a.y; f[ks * 8 + 2] = a.z; f[ks * 8 + 3] = a.w;
      f[ks * 8 + 4] = b.x; f[ks * 8 + 5] = b.y; f[ks * 8 + 6] = b.z; f[ks * 8 + 7] = b.w;
    }
    float ss = 0.f;
#pragma unroll
    for (int i = 0; i < 32; ++i) ss += f[i] * f[i];
    ss += __shfl_xor(ss, 16);
    ss += __shfl_xor(ss, 32);
    const float sc = (ss > 0.f ? rsqrtf(ss) : 0.f) * 1.44269504f;  // fold log2e
#pragma unroll
    for (int ks = 0; ks < 4; ++ks) {
      union { unsigned u[4]; bf16x8 v; } t;
#pragma unroll
      for (int p = 0; p < 4; ++p)
        t.u[p] = pkbf(f[ks * 8 + 2 * p] * sc, f[ks * 8 + 2 * p + 1] * sc);
      qf[qb][ks] = t.v;
    }
  }

  f32x4 acc[8][4];   // O^T accumulators [db][qb]
#pragma unroll
  for (int db = 0; db < 8; ++db)
#pragma unroll
    for (int qb = 0; qb < 4; ++qb) acc[db][qb] = (f32x4){0.f, 0.f, 0.f, 0.f};
  float den[4] = {0.f, 0.f, 0.f, 0.f};

  const int nIter = K >> 6;

  // stage 64-key Kn tile with key-permutation pi and chunk swizzle.
  // LDS row m <- key kt + (m&32) + g(m)*8 + kb(m)*4 + r(m); chunk j at j^(m&15).
  auto stage = [&](int it, int buf) {
#pragma unroll
    for (int i = 0; i < 8; ++i) {
      const int ii = wave * 8 + i;
      const int m = ii * 4 + (lane >> 4);
      const int j = (lane & 15) ^ (m & 15);
      const int keyoff =
          (m & 32) + ((m >> 2) & 3) * 8 + ((m >> 4) & 1) * 4 + (m & 3);
      ASYNC_CP16(knb + (size_t)((it << 6) + keyoff) * 256 + j * 16,
                 sK[buf] + ii * 1024);
    }
  };

  stage(0, 0);
  for (int it = 0; it < nIter; ++it) {
    const int buf = it & 1;
    __syncthreads();                       // stage(it) landed; prev reads done
    if (it + 1 < nIter) stage(it + 1, buf ^ 1);
    const int kt = it << 6;

#pragma unroll
    for (int h = 0; h < 2; ++h) {          // 32-key half-tiles
      // ---- S^T = Kn . Qn^T ------------------------------------------------
      f32x4 S[4][2];
#pragma unroll
      for (int qb = 0; qb < 4; ++qb) {
        S[qb][0] = (f32x4){0.f, 0.f, 0.f, 0.f};
        S[qb][1] = (f32x4){0.f, 0.f, 0.f, 0.f};
      }
#pragma unroll
      for (int ks = 0; ks < 4; ++ks) {
        const bf16x8 k0 = *(const bf16x8*)(sK[buf] + (h * 32 + c) * 256 +
                                           (((ks * 4 + g) ^ c) << 4));
        const bf16x8 k1 = *(const bf16x8*)(sK[buf] + (h * 32 + 16 + c) * 256 +
                                           (((ks * 4 + g) ^ c) << 4));
#pragma unroll
        for (int qb = 0; qb < 4; ++qb) {
          S[qb][0] = MFMA16(k0, qf[qb][ks], S[qb][0]);
          S[qb][1] = MFMA16(k1, qf[qb][ks], S[qb][1]);
        }
      }

      // ---- vf first half (issue early: covers L2 latency under exp) -------
      bf16x8 vfa[4];
#pragma unroll
      for (int db = 0; db < 4; ++db)
        vfa[db] = *(const bf16x8*)(vt + ((size_t)(db * 16 + c) * K + kt +
                                         h * 32 + g * 8) * 2);

      // ---- P = exp2(S) -> bf16 B-fragments (pi makes this pure packing) ---
      union { unsigned u[4]; bf16x8 v; } pf[4];
#pragma unroll
      for (int qb = 0; qb < 4; ++qb) {
        const float e0 = __builtin_amdgcn_exp2f(S[qb][0][0]);
        const float e1 = __builtin_amdgcn_exp2f(S[qb][0][1]);
        const float e2 = __builtin_amdgcn_exp2f(S[qb][0][2]);
        const float e3 = __builtin_amdgcn_exp2f(S[qb][0][3]);
        const float e4 = __builtin_amdgcn_exp2f(S[qb][1][0]);
        const float e5 = __builtin_amdgcn_exp2f(S[qb][1][1]);
        const float e6 = __builtin_amdgcn_exp2f(S[qb][1][2]);
        const float e7 = __builtin_amdgcn_exp2f(S[qb][1][3]);
        den[qb] += ((e0 + e1) + (e2 + e3)) + ((e4 + e5) + (e6 + e7));
        pf[qb].u[0] = pkbf(e0, e1);
        pf[qb].u[1] = pkbf(e2, e3);
        pf[qb].u[2] = pkbf(e4, e5);
        pf[qb].u[3] = pkbf(e6, e7);
      }

      // ---- vf second half, then O^T += V^T.P^T ----------------------------
      bf16x8 vfb[4];
#pragma unroll
      for (int db = 0; db < 4; ++db)
        vfb[db] = *(const bf16x8*)(vt + ((size_t)((db + 4) * 16 + c) * K + kt +
                                         h * 32 + g * 8) * 2);
#pragma unroll
      for (int db = 0; db < 4; ++db)
#pragma unroll
        for (int qb = 0; qb < 4; ++qb)
          acc[db][qb] = MFMA16(vfa[db], pf[qb].v, acc[db][qb]);
#pragma unroll
      for (int db = 0; db < 4; ++db)
#pragma unroll
        for (int qb = 0; qb < 4; ++qb)
          acc[db + 4][qb] = MFMA16(vfb[db], pf[qb].v, acc[db + 4][qb]);
    }
  }

  // ---- epilogue: den reduce, scale, per-wave LDS transpose, coalesced out --
  float rd[4];
#pragma unroll
  for (int qb = 0; qb < 4; ++qb) {
    float d = den[qb];
    d += __shfl_xor(d, 16);
    d += __shfl_xor(d, 32);
    rd[qb] = 1.0f / d;
  }
  __syncthreads();   // all waves done reading sK
  char* wls = sK[0] + wave * 5120;   // 64 rows x 80B per wave

#pragma unroll
  for (int db = 0; db < 8; ++db) {
#pragma unroll
    for (int qb = 0; qb < 4; ++qb)
#pragma unroll
      for (int pr = 0; pr < 2; ++pr) {
        float2 v;
        v.x = acc[db][qb][2 * pr] * rd[qb];
        v.y = acc[db][qb][2 * pr + 1] * rd[qb];
        *(float2*)(wls + (qb * 16 + c) * 80 + (g * 4 + 2 * pr) * 4) = v;
      }
    // same-wave write->read: compiler inserts lgkmcnt waits
#pragma unroll
    for (int i = 0; i < 4; ++i) {
      const int row = (lane & 15) + i * 16;
      const float4 v = *(const float4*)(wls + row * 80 + (lane >> 4) * 16);
      *(float4*)(out + (size_t)(qrow0 + row) * 128 + db * 16 + (lane >> 4) * 4) = v;
    }
  }
}

// ---------------------------------------------------------------------------
extern "C" void kernel_launch(void* const* d_in, const int* in_sizes, int n_in,
                              void* d_out, int out_size, void* d_ws, size_t ws_size,
                              hipStream_t stream) {
  const float* q = (const float*)d_in[0];
  const float* k = (const float*)d_in[1];
  const int N = in_sizes[0] / 128;   // 65536
  const int K = in_sizes[1] / 128;   // 4096
  char* ws = (char*)d_ws;
  unsigned* knb = (unsigned*)ws;                          // 1 MB
  unsigned* vt = (unsigned*)(ws + (size_t)K * 256);       // 1 MB
  float* out = (float*)d_out;

  prep_k<<<dim3(K / 64), dim3(256), 0, stream>>>(k, knb, vt, K);
  attn_main<<<dim3(N / 128), dim3(128), 0, stream>>>(q, (const char*)knb,
                                                     (const char*)vt, out, K);
}

// Round 3
// 222.248 us; speedup vs baseline: 4.5508x; 4.5508x over previous
//
#include <hip/hip_runtime.h>
#include <hip/hip_bf16.h>
#include <stdint.h>

// ---------------------------------------------------------------------------
// O = softmax(q_n . k_n^T) @ keys_raw   (N=65536, K=4096, D=128)
// 32x32x16 MFMA, transposed scheme: S^T = Kn.Qn^T, O^T = V^T.P^T.
// Key-permutation pi folded into vtf packing so S^T output regs ARE the PV
// B-fragment after exp+pack. All operands pre-packed in MFMA fragment order:
//   knf blob (tile64, t, ds):   lane -> Kn[t*32+c32][ds*16+h5*8+j]      (LDS)
//   vtf blob (tile64, s, db2):  lane -> Kraw[pi(s,h5,j)][db2*32+c32]    (L2)
// wave = 32 q-rows; 256-thr blocks; grid 512 (2 blocks/CU, 8 waves/CU).
// ---------------------------------------------------------------------------

typedef __attribute__((ext_vector_type(8))) short bf16x8;
typedef __attribute__((ext_vector_type(16))) float f32x16;

#define MFMA32(a, b, c) __builtin_amdgcn_mfma_f32_32x32x16_bf16(a, b, c, 0, 0, 0)
#define ASYNC_CP16(gsrc, ldst)                                                  \
  __builtin_amdgcn_global_load_lds(                                             \
      (const __attribute__((address_space(1))) void*)(gsrc),                    \
      (__attribute__((address_space(3))) void*)(ldst), 16, 0, 0)

__device__ __forceinline__ unsigned pkbf(float lo, float hi) {
  union { __hip_bfloat162 h2; unsigned u; } v;
  v.h2 = __float22bfloat162_rn(float2{lo, hi});
  return v.u;
}

// ---------------- prep_k: fragment-pack Kn (normalized) and V^T (raw) -------
__global__ __launch_bounds__(256) void prep_k(const float* __restrict__ k,
                                              char* __restrict__ knf,
                                              char* __restrict__ vtf, int K) {
  __shared__ float sRaw[64 * 132];
  __shared__ float sScale[64];
  const int tid = threadIdx.x;
  const int kbase = blockIdx.x * 64;
  {
    const int key_loc = tid >> 2, dq = tid & 3;
    const float4* src = (const float4*)(k + (size_t)(kbase + key_loc) * 128 + dq * 32);
    float4 f[8];
    float ss = 0.f;
#pragma unroll
    for (int i = 0; i < 8; ++i) {
      f[i] = src[i];
      ss += f[i].x * f[i].x + f[i].y * f[i].y + f[i].z * f[i].z + f[i].w * f[i].w;
    }
    ss += __shfl_xor(ss, 1);
    ss += __shfl_xor(ss, 2);
    float4* dst = (float4*)(sRaw + key_loc * 132 + dq * 32);
#pragma unroll
    for (int i = 0; i < 8; ++i) dst[i] = f[i];
    if (dq == 0) sScale[key_loc] = ss > 0.f ? rsqrtf(ss) : 0.f;
  }
  __syncthreads();

  // knf: 1024 chunks of 16B per 64-key block
#pragma unroll
  for (int r = 0; r < 4; ++r) {
    const int c = r * 256 + tid;
    const int t_loc = c >> 9, ds = (c >> 6) & 7, l = c & 63;
    const int h5 = l >> 5, c32 = l & 31;
    const int key_loc = t_loc * 32 + c32;
    const float sc = sScale[key_loc];
    const float* p = sRaw + key_loc * 132 + ds * 16 + h5 * 8;
    uint4 w;
    w.x = pkbf(p[0] * sc, p[1] * sc);
    w.y = pkbf(p[2] * sc, p[3] * sc);
    w.z = pkbf(p[4] * sc, p[5] * sc);
    w.w = pkbf(p[6] * sc, p[7] * sc);
    *(uint4*)(knf + ((size_t)blockIdx.x * 1024 + c) * 16) = w;
  }
  // vtf: 1024 chunks; pi(s,h5,j) = (s>>1)*32 + (s&1)*8 + h5*4 + (j&3) + 16*(j>>2)
#pragma unroll
  for (int r = 0; r < 4; ++r) {
    const int c = r * 256 + tid;
    const int s = c >> 8, db2 = (c >> 6) & 3, l = c & 63;
    const int h5 = l >> 5, c32 = l & 31;
    const int d = db2 * 32 + c32;
    const int kb = (s >> 1) * 32 + (s & 1) * 8 + h5 * 4;
    float f[8];
#pragma unroll
    for (int j = 0; j < 8; ++j)
      f[j] = sRaw[(kb + (j & 3) + (j >> 2) * 16) * 132 + d];
    uint4 w;
    w.x = pkbf(f[0], f[1]);
    w.y = pkbf(f[2], f[3]);
    w.z = pkbf(f[4], f[5]);
    w.w = pkbf(f[6], f[7]);
    *(uint4*)(vtf + ((size_t)blockIdx.x * 1024 + c) * 16) = w;
  }
}

// ----------------------------- fused attention ------------------------------
__global__ __launch_bounds__(256, 2) void attn_main(
    const float* __restrict__ q, const char* __restrict__ knf,
    const char* __restrict__ vtf, float* __restrict__ out, int K) {
  __shared__ __align__(16) char sK[2][16384];
  const int tid = threadIdx.x;
  const int wave = tid >> 6, lane = tid & 63;
  const int h5 = lane >> 5, c32 = lane & 31;
  const int qrow0 = blockIdx.x * 128 + wave * 32;

  // ---- Q: load row (qrow0+c32), normalize, fold log2e, pack B-fragments ---
  bf16x8 qf[8];
  {
    const float* qr = q + (size_t)(qrow0 + c32) * 128;
    float f[64];
    float ss = 0.f;
#pragma unroll
    for (int ds = 0; ds < 8; ++ds) {
      const float4 a = *(const float4*)(qr + ds * 16 + h5 * 8);
      const float4 b = *(const float4*)(qr + ds * 16 + h5 * 8 + 4);
      f[ds * 8 + 0] = a.x; f[ds * 8 + 1] = a.y; f[ds * 8 + 2] = a.z; f[ds * 8 + 3] = a.w;
      f[ds * 8 + 4] = b.x; f[ds * 8 + 5] = b.y; f[ds * 8 + 6] = b.z; f[ds * 8 + 7] = b.w;
    }
#pragma unroll
    for (int i = 0; i < 64; ++i) ss += f[i] * f[i];
    ss += __shfl_xor(ss, 32);
    const float sc = (ss > 0.f ? rsqrtf(ss) : 0.f) * 1.44269504f;
#pragma unroll
    for (int ds = 0; ds < 8; ++ds) {
      union { unsigned u[4]; bf16x8 v; } t;
#pragma unroll
      for (int p = 0; p < 4; ++p)
        t.u[p] = pkbf(f[ds * 8 + 2 * p] * sc, f[ds * 8 + 2 * p + 1] * sc);
      qf[ds] = t.v;
    }
  }

  f32x16 acc[4];
#pragma unroll
  for (int db2 = 0; db2 < 4; ++db2)
#pragma unroll
    for (int r = 0; r < 16; ++r) acc[db2][r] = 0.f;
  float den = 0.f;

  const int nIter = K >> 6;
  auto stage = [&](int it, int buf) {
#pragma unroll
    for (int i = 0; i < 4; ++i)
      ASYNC_CP16(knf + (size_t)it * 16384 + (wave * 4 + i) * 1024 + lane * 16,
                 sK[buf] + (wave * 4 + i) * 1024);
  };

  stage(0, 0);
  for (int it = 0; it < nIter; ++it) {
    const int buf = it & 1;
    __syncthreads();                      // stage(it) drained; prev reads done
    if (it + 1 < nIter) stage(it + 1, buf ^ 1);

    // ---- S^T = Kn . Qn^T : 2 tiles of [32 keys][32 q] ----------------------
    f32x16 S[2];
#pragma unroll
    for (int t = 0; t < 2; ++t) {
      f32x16 s;
#pragma unroll
      for (int r = 0; r < 16; ++r) s[r] = 0.f;
#pragma unroll
      for (int ds = 0; ds < 8; ++ds) {
        const bf16x8 kf = *(const bf16x8*)(sK[buf] + (t * 8 + ds) * 1024 + lane * 16);
        s = MFMA32(kf, qf[ds], s);
      }
      S[t] = s;
    }

    // ---- PV: O^T += V^T.P^T, 4 k-steps of 16 keys, vf from L2 --------------
    const char* vbase = vtf + (size_t)it * 16384;
    bf16x8 vcur[4], vnxt[4];
#pragma unroll
    for (int db2 = 0; db2 < 4; ++db2)
      vcur[db2] = *(const bf16x8*)(vbase + db2 * 1024 + lane * 16);
#pragma unroll
    for (int s = 0; s < 4; ++s) {
      if (s < 3)
#pragma unroll
        for (int db2 = 0; db2 < 4; ++db2)
          vnxt[db2] = *(const bf16x8*)(vbase + ((s + 1) * 4 + db2) * 1024 + lane * 16);
      const int t = s >> 1, w = s & 1;
      float e[8];
#pragma unroll
      for (int j = 0; j < 8; ++j) {
        const int rr = w * 4 + (j & 3) + (j >> 2) * 8;
        e[j] = __builtin_amdgcn_exp2f(S[t][rr]);
      }
      den += ((e[0] + e[1]) + (e[2] + e[3])) + ((e[4] + e[5]) + (e[6] + e[7]));
      union { unsigned u[4]; bf16x8 v; } pf;
#pragma unroll
      for (int j2 = 0; j2 < 4; ++j2) pf.u[j2] = pkbf(e[2 * j2], e[2 * j2 + 1]);
#pragma unroll
      for (int db2 = 0; db2 < 4; ++db2)
        acc[db2] = MFMA32(vcur[db2], pf.v, acc[db2]);
      if (s < 3)
#pragma unroll
        for (int db2 = 0; db2 < 4; ++db2) vcur[db2] = vnxt[db2];
    }
  }

  den += __shfl_xor(den, 32);
  const float rd = 1.0f / den;

  // ---- epilogue: per-wave LDS transpose (XOR-swizzled), coalesced stores ---
  __syncthreads();                        // all waves done with sK
  float* wls = (float*)(&sK[0][0] + wave * 4096);   // 32 q-rows x 32 floats
#pragma unroll
  for (int db2 = 0; db2 < 4; ++db2) {
#pragma unroll
    for (int qd = 0; qd < 4; ++qd) {
      float4 v;
      v.x = acc[db2][qd * 4 + 0] * rd;
      v.y = acc[db2][qd * 4 + 1] * rd;
      v.z = acc[db2][qd * 4 + 2] * rd;
      v.w = acc[db2][qd * 4 + 3] * rd;
      *(float4*)(wls + c32 * 32 + (((h5 + 2 * qd) ^ (c32 & 7)) << 2)) = v;
    }
#pragma unroll
    for (int p = 0; p < 4; ++p) {
      const int ql = p * 8 + (lane >> 3);
      const int x = lane & 7;
      const float4 v = *(const float4*)(wls + ql * 32 + ((x ^ (ql & 7)) << 2));
      *(float4*)(out + (size_t)(qrow0 + ql) * 128 + db2 * 32 + x * 4) = v;
    }
  }
}

// ---------------------------------------------------------------------------
extern "C" void kernel_launch(void* const* d_in, const int* in_sizes, int n_in,
                              void* d_out, int out_size, void* d_ws, size_t ws_size,
                              hipStream_t stream) {
  const float* q = (const float*)d_in[0];
  const float* k = (const float*)d_in[1];
  const int N = in_sizes[0] / 128;   // 65536
  const int K = in_sizes[1] / 128;   // 4096
  char* ws = (char*)d_ws;
  char* knf = ws;                          // K*256 B = 1 MB
  char* vtf = ws + (size_t)K * 256;        // 1 MB
  float* out = (float*)d_out;

  prep_k<<<dim3(K / 64), dim3(256), 0, stream>>>(k, knf, vtf, K);
  attn_main<<<dim3(N / 128), dim3(256), 0, stream>>>(q, knf, vtf, out, K);
}